// Round 2
// baseline (720.077 us; speedup 1.0000x reference)
//
#include <hip/hip_runtime.h>
#include <cstdint>

#define B 32
#define D 8732
#define C 21
#define L 32
#define O 8
#define NS 8
#define SLICE 1092     // ceil(D/8)
#define NT 1024

struct Ws {
  const float *loc, *conf, *line, *pose, *dbox, *targets;
  float* out;
  int* bar;                 // [0..31] per-batch, [32]=A, [33]=B, [34]=C (zeroed by memset)
  unsigned long long* bp;   // 256*O per-(batch,slice) best-prior partial keys (no atomics)
  int* cnt;                 // 256 per-(b,slice) positive count (uncapped)
  int* posSlice;            // 256*256 packed (d | cls<<14 | bi<<19)
  float* sce;               // B*D mined-ce
  double *gLossL, *gLossP, *gCeP;                  // 256 partials
  double *gCeNeg;                                  // 32
  double *gDesk, *gNpp, *gNnp, *gTripS, *gTripC;   // 256
  int* gPc;                 // 1
  float *emb, *nemb, *qp; int* lab;                // 256-row gathered
};

__device__ inline double waveSumD(double v) {
  #pragma unroll
  for (int s = 32; s > 0; s >>= 1) v += __shfl_down(v, s, 64);
  return v;
}

__device__ inline float iou_one(float tx1, float ty1, float tx2, float ty2, float ta,
                                float px1, float py1, float px2, float py2, float areaB) {
  float lx = fmaxf(tx1, px1), ly = fmaxf(ty1, py1);
  float rx = fminf(tx2, px2), ry = fminf(ty2, py2);
  float iw = fmaxf(rx - lx, 0.f), ih = fmaxf(ry - ly, 0.f);
  float inter = iw * ih;
  return inter / (ta + areaB - inter);
}

// ---- lightweight device-scope barriers (co-residency via cooperative launch) ----
__device__ inline void arriveBar(int* ctr) {
  __threadfence();               // release: publish this block's prior writes
  __syncthreads();
  if (threadIdx.x == 0)
    __hip_atomic_fetch_add(ctr, 1, __ATOMIC_ACQ_REL, __HIP_MEMORY_SCOPE_AGENT);
}
__device__ inline void waitBar(int* ctr, int target) {
  if (threadIdx.x == 0) {
    while (__hip_atomic_load(ctr, __ATOMIC_ACQUIRE, __HIP_MEMORY_SCOPE_AGENT) < target)
      __builtin_amdgcn_s_sleep(1);
  }
  __syncthreads();
  __threadfence();               // acquire: subsequent loads see published data
}

// Per-phase shared layouts, overlaid in a union (phases are sequential).
struct ShA {                    // phase 0 (best-prior) + phase 1 (slice)
  float tb[O][4], ta[O], tl[O], tp_[O][3];
  unsigned long long wm[16][O];
  int bpd[O];
  int plist[256];
  int wcnt[16], wbase[16];
  double wred[16][3];
  int run;
};
struct __align__(16) ShB {      // phase 2 (per-batch top-k + gather)
  float sce[D];
  int whist[16][256];
  int hist[256];
  int sc[256];
  int p8[NS + 1];
  int gbS;
  unsigned prefixSh; int kkSh;
  double wsum[16], wcnt2[16];
};
struct ShC {                    // phase 3 (pairs + triplet)
  float ei[L], ni[L], qi[3];
  float sd[256];
  unsigned long long spm[4], snm[4];
  double w1[4];
  int ppc[4], npc[4];
  double wS[16], wC[16];
  int liS, pcS;
};
struct ShD { double lbuf[16]; int last; };  // phase 4 (final reduce)
union ShU { ShA a; ShB b; ShC c; ShD d; };

__global__ __launch_bounds__(NT, 4) void k_all(Ws p) {
  __shared__ ShU sh;
  int g = blockIdx.x, tid = threadIdx.x;
  int lane = tid & 63, wav = tid >> 6;
  int b = g >> 3, s = g & 7;
  int dBeg = s * SLICE;
  int dEnd = dBeg + SLICE; if (dEnd > D) dEnd = D;

  // ---- load targets for this batch (used by phases 0 and 1) ----
  if (tid < O) {
    const float* tr = p.targets + ((size_t)b * O + tid) * 9;
    sh.a.tb[tid][0] = tr[0]; sh.a.tb[tid][1] = tr[1];
    sh.a.tb[tid][2] = tr[2]; sh.a.tb[tid][3] = tr[3];
    sh.a.ta[tid] = (tr[2] - tr[0]) * (tr[3] - tr[1]);
    sh.a.tl[tid] = tr[4];
    sh.a.tp_[tid][0] = tr[5]; sh.a.tp_[tid][1] = tr[6]; sh.a.tp_[tid][2] = tr[7];
  }
  __syncthreads();

  // ============ phase 0: per-(b,slice) best-prior partial keys ============
  {
    unsigned long long key[O];
    #pragma unroll
    for (int t = 0; t < O; t++) key[t] = 0ull;
    for (int d = dBeg + tid; d < dEnd; d += NT) {
      float4 db = *(const float4*)(p.dbox + (size_t)d * 4);
      float px1 = db.x - 0.5f*db.z, py1 = db.y - 0.5f*db.w;
      float px2 = db.x + 0.5f*db.z, py2 = db.y + 0.5f*db.w;
      float areaB = db.z * db.w;
      #pragma unroll
      for (int t = 0; t < O; t++) {
        float iou = iou_one(sh.a.tb[t][0], sh.a.tb[t][1], sh.a.tb[t][2], sh.a.tb[t][3],
                            sh.a.ta[t], px1, py1, px2, py2, areaB);
        unsigned long long kk = ((unsigned long long)__float_as_uint(iou) << 32)
                              | (unsigned long long)(0xFFFFFFFFu - (unsigned)d); // tie -> smaller d
        if (kk > key[t]) key[t] = kk;
      }
    }
    #pragma unroll
    for (int t = 0; t < O; t++) {
      unsigned long long k = key[t];
      #pragma unroll
      for (int sft = 32; sft > 0; sft >>= 1) {
        unsigned long long o = __shfl_down(k, sft, 64);
        if (o > k) k = o;
      }
      if (lane == 0) sh.a.wm[wav][t] = k;
    }
    __syncthreads();
    if (tid < O) {
      unsigned long long k = sh.a.wm[0][tid];
      #pragma unroll
      for (int w = 1; w < 16; w++) if (sh.a.wm[w][tid] > k) k = sh.a.wm[w][tid];
      p.bp[g * O + tid] = k;
    }
  }
  // per-batch barrier: 8 slice-blocks of batch b
  arriveBar(&p.bar[b]);
  waitBar(&p.bar[b], 8);

  // ============ phase 1: match/CE/losses/compaction ============
  {
    if (tid < O) {
      unsigned long long k = 0ull;
      #pragma unroll
      for (int ss = 0; ss < NS; ss++) {
        unsigned long long kk = p.bp[(b * NS + ss) * O + tid];
        if (kk > k) k = kk;
      }
      sh.a.bpd[tid] = (int)(0xFFFFFFFFu - (unsigned)(k & 0xFFFFFFFFull));
    }
    if (tid == 0) sh.a.run = 0;
    __syncthreads();

    const unsigned long long lt = (lane == 0) ? 0ull : (~0ull >> (64 - lane));
    double ll = 0, lp = 0, cp = 0;
    for (int d0 = dBeg; d0 < dEnd; d0 += NT) {
      int d = d0 + tid;
      bool act = d < dEnd;
      int cls = 0, bi = 0;
      if (act) {
        float4 db = *(const float4*)(p.dbox + (size_t)d * 4);
        float px1 = db.x - 0.5f*db.z, py1 = db.y - 0.5f*db.w;
        float px2 = db.x + 0.5f*db.z, py2 = db.y + 0.5f*db.w;
        float areaB = db.z * db.w;
        float bv = -1.0f;
        #pragma unroll
        for (int t = 0; t < O; t++) {
          float iou = iou_one(sh.a.tb[t][0], sh.a.tb[t][1], sh.a.tb[t][2], sh.a.tb[t][3],
                              sh.a.ta[t], px1, py1, px2, py2, areaB);
          if (iou > bv) { bv = iou; bi = t; }     // argmax axis=0: first max wins
        }
        #pragma unroll
        for (int t = O - 1; t >= 0; t--)          // numpy scatter: last truth wins
          if (sh.a.bpd[t] == d) { bi = t; bv = 2.0f; break; }
        cls = (bv < 0.5f) ? 0 : ((int)sh.a.tl[bi] + 1);
        const float* cb = p.conf + ((size_t)b * D + d) * C;
        float x[C];
        #pragma unroll
        for (int c = 0; c < C; c++) x[c] = cb[c];
        float m = x[0];
        #pragma unroll
        for (int c = 1; c < C; c++) m = fmaxf(m, x[c]);
        float sm = 0.f;
        #pragma unroll
        for (int c = 0; c < C; c++) sm += __expf(x[c] - m);
        float xc = x[0];
        #pragma unroll
        for (int c = 1; c < C; c++) xc = (cls == c) ? x[c] : xc;
        float ce = m + __logf(sm) - xc;
        size_t bd = (size_t)b * D + d;
        if (cls > 0) {
          cp += ce;
          p.sce[bd] = 0.f;
          float g0 = ((sh.a.tb[bi][0] + sh.a.tb[bi][2]) * 0.5f - db.x) / (0.1f * db.z);
          float g1 = ((sh.a.tb[bi][1] + sh.a.tb[bi][3]) * 0.5f - db.y) / (0.1f * db.w);
          float g2 = logf((sh.a.tb[bi][2] - sh.a.tb[bi][0]) / db.z) / 0.2f;
          float g3 = logf((sh.a.tb[bi][3] - sh.a.tb[bi][1]) / db.w) / 0.2f;
          float4 lo = *(const float4*)(p.loc + bd * 4);
          float dv, a;
          dv = lo.x - g0; a = fabsf(dv); ll += (double)((a < 1.f) ? 0.5f*dv*dv : a - 0.5f);
          dv = lo.y - g1; a = fabsf(dv); ll += (double)((a < 1.f) ? 0.5f*dv*dv : a - 0.5f);
          dv = lo.z - g2; a = fabsf(dv); ll += (double)((a < 1.f) ? 0.5f*dv*dv : a - 0.5f);
          dv = lo.w - g3; a = fabsf(dv); ll += (double)((a < 1.f) ? 0.5f*dv*dv : a - 0.5f);
          const float* po = p.pose + bd * 3;
          #pragma unroll
          for (int q = 0; q < 3; q++) {
            float pd = po[q] - sh.a.tp_[bi][q];
            lp += (double)pd * (double)pd;
          }
        } else {
          p.sce[bd] = fmaxf(ce, 0.f);
        }
      }
      bool pos = act && (cls > 0);
      unsigned long long mm = __ballot(pos);
      if (lane == 0) sh.a.wcnt[wav] = __popcll(mm);
      __syncthreads();
      if (tid == 0) {
        int r = sh.a.run;
        #pragma unroll
        for (int w = 0; w < 16; w++) { sh.a.wbase[w] = r; r += sh.a.wcnt[w]; }
        sh.a.run = r;
      }
      __syncthreads();
      if (pos) {
        int rank = sh.a.wbase[wav] + __popcll(mm & lt);
        if (rank < 256) sh.a.plist[rank] = d | (cls << 14) | (bi << 19);
      }
      __syncthreads();
    }
    int tot = sh.a.run;
    if (tid == 0) p.cnt[g] = tot;
    int stored = (tot < 256) ? tot : 256;
    if (tid < stored) p.posSlice[g * 256 + tid] = sh.a.plist[tid];
    double a0 = waveSumD(ll), a1 = waveSumD(lp), a2 = waveSumD(cp);
    if (lane == 0) { sh.a.wred[wav][0] = a0; sh.a.wred[wav][1] = a1; sh.a.wred[wav][2] = a2; }
    __syncthreads();
    if (tid == 0) {
      double tll = 0, tlp = 0, tcp = 0;
      #pragma unroll
      for (int w = 0; w < 16; w++) { tll += sh.a.wred[w][0]; tlp += sh.a.wred[w][1]; tcp += sh.a.wred[w][2]; }
      p.gLossL[g] = tll; p.gLossP[g] = tlp; p.gCeP[g] = tcp;
    }
  }
  // barrier A: publish phase-1 results (all 256 blocks arrive)
  arriveBar(&p.bar[32]);

  // ============ phase 2: per-batch radix top-k + positive gather (blocks 0..31) ============
  if (g < B) {
    waitBar(&p.bar[32], 256);          // writers wait for ALL phase-1 results
    int bb = g;
    if (tid < 256) sh.b.sc[tid] = p.cnt[tid];
    __syncthreads();
    if (tid == 0) {
      int gb2 = 0;
      for (int i = 0; i < bb * NS; i++) gb2 += sh.b.sc[i];
      sh.b.gbS = gb2;
      int run2 = 0;
      for (int ss = 0; ss < NS; ss++) { sh.b.p8[ss] = run2; run2 += sh.b.sc[bb * NS + ss]; }
      sh.b.p8[NS] = run2;                       // npos of this batch
      if (bb == 0) {
        int totAll = 0;
        for (int i = 0; i < 256; i++) totAll += sh.b.sc[i];
        *p.gPc = (totAll < 256) ? totAll : 256;
      }
    }
    __syncthreads();
    int gb = sh.b.gbS, npos = sh.b.p8[NS];
    int nr = (npos < 256) ? npos : 256;
    if (tid < nr) {
      int r = tid, ss = 0;
      #pragma unroll
      for (int q = 1; q < NS; q++) if (r >= sh.b.p8[q]) ss = q;
      int idx = r - sh.b.p8[ss];
      int slot = gb + r;
      if (idx < 256 && slot < 256) {
        int packed = p.posSlice[(bb * NS + ss) * 256 + idx];
        int d   = packed & 0x3FFF;
        int cls = (packed >> 14) & 31;
        int bi  = (packed >> 19) & 7;
        size_t flat = (size_t)bb * D + d;
        const float4* e4 = (const float4*)(p.line + flat * L);
        float4* o4 = (float4*)(p.emb + slot * L);
        float4* n4 = (float4*)(p.nemb + slot * L);
        float4 v[8];
        float nrm2 = 0.f;
        #pragma unroll
        for (int c = 0; c < 8; c++) {
          v[c] = e4[c];
          o4[c] = v[c];
          nrm2 += v[c].x*v[c].x + v[c].y*v[c].y + v[c].z*v[c].z + v[c].w*v[c].w;
        }
        float inv = 1.f / fmaxf(sqrtf(nrm2), 1e-12f);
        #pragma unroll
        for (int c = 0; c < 8; c++) {
          float4 t = v[c];
          t.x *= inv; t.y *= inv; t.z *= inv; t.w *= inv;
          n4[c] = t;
        }
        p.lab[slot] = cls;
        const float* tr = p.targets + ((size_t)bb * O + bi) * 9;
        p.qp[slot * 3 + 0] = tr[5]; p.qp[slot * 3 + 1] = tr[6]; p.qp[slot * 3 + 2] = tr[7];
      }
    }
    // radix top-k over this batch's mined ce (k = 3*npos)
    const float* ce = p.sce + (size_t)bb * D;
    for (int i = tid; i < D / 4; i += NT)
      ((float4*)sh.b.sce)[i] = ((const float4*)ce)[i];
    int k = npos * 3; if (k > D) k = D;
    __syncthreads();
    unsigned prefix = 0; int kk = k;            // kk >= 1 (npos >= 1 via forced matches)
    for (int pass = 0; pass < 4; pass++) {
      int shift = 24 - 8 * pass;
      for (int i = tid; i < 16 * 256; i += NT) ((int*)sh.b.whist)[i] = 0;
      __syncthreads();
      unsigned himask = (pass == 0) ? 0u : (0xFFFFFFFFu << (shift + 8));
      for (int d = tid; d < D; d += NT) {
        unsigned keyb = __float_as_uint(sh.b.sce[d]);
        if ((keyb & himask) == (prefix & himask))
          atomicAdd(&sh.b.whist[wav][(keyb >> shift) & 255], 1);
      }
      __syncthreads();
      if (tid < 256) {
        int h = 0;
        #pragma unroll
        for (int w = 0; w < 16; w++) h += sh.b.whist[w][tid];
        sh.b.hist[tid] = h;
      }
      __syncthreads();
      if (tid < 64) {
        int l = tid;
        int h0 = sh.b.hist[l*4], h1 = sh.b.hist[l*4+1], h2 = sh.b.hist[l*4+2], h3 = sh.b.hist[l*4+3];
        int loc4 = h0 + h1 + h2 + h3;
        int suf = loc4;
        #pragma unroll
        for (int st = 1; st < 64; st <<= 1) {
          int o = __shfl_down(suf, st, 64);
          if (l + st < 64) suf += o;
        }
        int snext = suf - loc4;
        int s3 = snext + h3, s2 = s3 + h2, s1 = s2 + h1, s0 = s1 + h0;
        if (s3 >= kk && snext < kk) { sh.b.prefixSh = prefix | ((unsigned)(l*4+3) << shift); sh.b.kkSh = kk - snext; }
        if (s2 >= kk && s3 < kk)    { sh.b.prefixSh = prefix | ((unsigned)(l*4+2) << shift); sh.b.kkSh = kk - s3; }
        if (s1 >= kk && s2 < kk)    { sh.b.prefixSh = prefix | ((unsigned)(l*4+1) << shift); sh.b.kkSh = kk - s2; }
        if (s0 >= kk && s1 < kk)    { sh.b.prefixSh = prefix | ((unsigned)(l*4+0) << shift); sh.b.kkSh = kk - s1; }
      }
      __syncthreads();
      prefix = sh.b.prefixSh; kk = sh.b.kkSh;
      __syncthreads();
    }
    float T = __uint_as_float(prefix);
    double sgt = 0.0; int cgt = 0;
    for (int d = tid; d < D; d += NT) {
      float v = sh.b.sce[d];
      if (__float_as_uint(v) > prefix) { sgt += (double)v; cgt++; }
    }
    double wv = waveSumD(sgt);
    double wc = waveSumD((double)cgt);
    if (lane == 0) { sh.b.wsum[wav] = wv; sh.b.wcnt2[wav] = wc; }
    __syncthreads();
    if (tid == 0) {
      double tsg = 0, tcg = 0;
      #pragma unroll
      for (int w = 0; w < 16; w++) { tsg += sh.b.wsum[w]; tcg += sh.b.wcnt2[w]; }
      p.gCeNeg[bb] = tsg + ((double)k - tcg) * (double)T;
    }
    // barrier B: 32 writers publish gather results
    arriveBar(&p.bar[33]);
  }
  // everyone (writers included) waits for all 32 phase-2 writers
  waitBar(&p.bar[33], 32);

  // ============ phase 3: pairs + triplet, block i = row i ============
  {
    int i = g;
    int qq = tid >> 8, j = tid & 255;
    if (tid == 0) { sh.c.pcS = *p.gPc; sh.c.liS = p.lab[i]; }
    if (tid < L) { sh.c.ei[tid] = p.emb[i * L + tid]; sh.c.ni[tid] = p.nemb[i * L + tid]; }
    if (tid >= L && tid < L + 3) sh.c.qi[tid - L] = p.qp[i * 3 + (tid - L)];
    __syncthreads();
    int Pc = sh.c.pcS, li = sh.c.liS;
    bool vi = (i < Pc);
    bool pp = false, np = false;
    double dsk = 0.0;
    if (qq == 0) {
      bool vj = (j < Pc);
      const float4* nj4 = (const float4*)(p.nemb + j * L);
      const float4* ej4 = (const float4*)(p.emb + j * L);
      float sq = 0.f, esq = 0.f;
      #pragma unroll
      for (int c = 0; c < 8; c++) {
        float4 nn = nj4[c], ee = ej4[c];
        float d0 = sh.c.ni[c*4+0] - nn.x, d1 = sh.c.ni[c*4+1] - nn.y;
        float d2 = sh.c.ni[c*4+2] - nn.z, d3 = sh.c.ni[c*4+3] - nn.w;
        sq += d0*d0 + d1*d1 + d2*d2 + d3*d3;
        float e0 = sh.c.ei[c*4+0] - ee.x, e1 = sh.c.ei[c*4+1] - ee.y;
        float e2 = sh.c.ei[c*4+2] - ee.z, e3 = sh.c.ei[c*4+3] - ee.w;
        esq += e0*e0 + e1*e1 + e2*e2 + e3*e3;
      }
      float dd = sqrtf(fmaxf(sq, 1e-12f));
      sh.c.sd[j] = dd;
      float qsq = 0.f;
      #pragma unroll
      for (int c = 0; c < 3; c++) { float dq = sh.c.qi[c] - p.qp[j * 3 + c]; qsq += dq * dq; }
      bool vp = vi && vj && (i != j);
      bool same = (li == p.lab[j]);
      pp = vp && same && (dd > 0.2f);
      np = vp && !same && (dd < 0.8f);
      float diff = esq - qsq;
      dsk = pp ? (double)diff * (double)diff : 0.0;
    }
    unsigned long long pb = __ballot(pp), nb = __ballot(np);
    double dw = waveSumD(dsk);
    if (lane == 0 && wav < 4) {
      sh.c.spm[wav] = pb; sh.c.snm[wav] = nb; sh.c.w1[wav] = dw;
      sh.c.ppc[wav] = (int)__popcll(pb); sh.c.npc[wav] = (int)__popcll(nb);
    }
    __syncthreads();
    unsigned long long pmw = sh.c.spm[j >> 6];
    bool pj = (pmw >> (j & 63)) & 1ull;
    float sdj = sh.c.sd[j];
    double ts = 0.0, tc = 0.0;
    if (pj) {
      for (int it = 0; it < 64; it++) {
        int kx = qq + 4 * it;
        unsigned long long nmw = sh.c.snm[kx >> 6];
        if ((nmw >> (kx & 63)) & 1ull) {
          float x = sdj - sh.c.sd[kx] + 0.2f;
          if (x > 0.f) { ts += (double)x; tc += 1.0; }
        }
      }
    }
    ts = waveSumD(ts); tc = waveSumD(tc);
    if (lane == 0) { sh.c.wS[wav] = ts; sh.c.wC[wav] = tc; }
    __syncthreads();
    if (tid == 0) {
      double S = 0, Cc = 0;
      #pragma unroll
      for (int w = 0; w < 16; w++) { S += sh.c.wS[w]; Cc += sh.c.wC[w]; }
      double dsum = sh.c.w1[0] + sh.c.w1[1] + sh.c.w1[2] + sh.c.w1[3];
      int pcnt = sh.c.ppc[0] + sh.c.ppc[1] + sh.c.ppc[2] + sh.c.ppc[3];
      int ncnt = sh.c.npc[0] + sh.c.npc[1] + sh.c.npc[2] + sh.c.npc[3];
      p.gDesk[i] = dsum; p.gNpp[i] = (double)pcnt; p.gNnp[i] = (double)ncnt;
      p.gTripS[i] = S; p.gTripC[i] = Cc;
    }
  }

  // ============ phase 4: last-arriver does final reduce (no grid barrier) ============
  __threadfence();
  __syncthreads();
  if (tid == 0) {
    int prev = __hip_atomic_fetch_add(&p.bar[34], 1, __ATOMIC_ACQ_REL, __HIP_MEMORY_SCOPE_AGENT);
    sh.d.last = (prev == 255);
  }
  __syncthreads();
  if (!sh.d.last) return;
  __threadfence();   // acquire all other blocks' phase-3 writes
  {
    auto sumD = [&](const double* a, int n) -> double {
      double v = 0;
      for (int i = tid; i < n; i += NT) v += a[i];
      v = waveSumD(v);
      __syncthreads();
      if (lane == 0) sh.d.lbuf[wav] = v;
      __syncthreads();
      double r = 0;
      #pragma unroll
      for (int w = 0; w < 16; w++) r += sh.d.lbuf[w];
      __syncthreads();
      return r;
    };
    double lossL = sumD(p.gLossL, 256);
    double lossP = sumD(p.gLossP, 256);
    double ceP   = sumD(p.gCeP,   256);
    double ceN   = sumD(p.gCeNeg,  B);
    double desk  = sumD(p.gDesk,  256);
    double npp   = sumD(p.gNpp,   256);
    double nnp   = sumD(p.gNnp,   256);
    double tripS = sumD(p.gTripS, 256);
    double tripC = sumD(p.gTripC, 256);
    double Ntot;
    {
      double v = 0;
      for (int i = tid; i < 256; i += NT) v += (double)p.cnt[i];
      v = waveSumD(v);
      __syncthreads();
      if (lane == 0) sh.d.lbuf[wav] = v;
      __syncthreads();
      Ntot = 0;
      #pragma unroll
      for (int w = 0; w < 16; w++) Ntot += sh.d.lbuf[w];
    }
    if (tid == 0) {
      double N = (Ntot > 0.0) ? Ntot : 1.0;
      p.out[0] = (float)(lossL / N);
      p.out[1] = (float)((ceP + ceN) / N);
      p.out[2] = (float)(lossP / N);
      double cnt = (tripC > 0.0) ? tripC : 1.0;
      double loss_t = tripS / cnt;
      double nppd = (npp > 0.0) ? npp : 1.0;
      double tot = npp + nnp;
      double denom = (tot > 0.0) ? tot : 1.0;
      double Ldesk = desk / nppd + loss_t / denom;
      Ldesk = Ldesk / nppd / 32.0;
      p.out[3] = (float)Ldesk;
      p.out[4] = (float)loss_t;
    }
  }
}

extern "C" void kernel_launch(void* const* d_in, const int* in_sizes, int n_in,
                              void* d_out, int out_size, void* d_ws, size_t ws_size,
                              hipStream_t stream) {
  char* ws = (char*)d_ws;
  size_t off = 0;
  auto alloc = [&](size_t bytes) -> char* {
    char* q = ws + off;
    off += (bytes + 255) & ~(size_t)255;
    return q;
  };
  Ws p;
  p.loc     = (const float*)d_in[0];
  p.conf    = (const float*)d_in[1];
  p.line    = (const float*)d_in[2];
  p.pose    = (const float*)d_in[3];
  p.dbox    = (const float*)d_in[4];
  p.targets = (const float*)d_in[5];
  p.out     = (float*)d_out;
  p.bar      = (int*)alloc(64 * 4);
  p.bp       = (unsigned long long*)alloc(256 * O * 8);
  p.cnt      = (int*)alloc(256 * 4);
  p.posSlice = (int*)alloc(256 * 256 * 4);
  p.sce      = (float*)alloc((size_t)B * D * 4);
  p.gLossL   = (double*)alloc(256 * 8);
  p.gLossP   = (double*)alloc(256 * 8);
  p.gCeP     = (double*)alloc(256 * 8);
  p.gCeNeg   = (double*)alloc(B * 8);
  p.gDesk    = (double*)alloc(256 * 8);
  p.gNpp     = (double*)alloc(256 * 8);
  p.gNnp     = (double*)alloc(256 * 8);
  p.gTripS   = (double*)alloc(256 * 8);
  p.gTripC   = (double*)alloc(256 * 8);
  p.gPc      = (int*)alloc(256);
  p.emb      = (float*)alloc(256 * L * 4);
  p.nemb     = (float*)alloc(256 * L * 4);
  p.qp       = (float*)alloc(256 * 3 * 4);
  p.lab      = (int*)alloc(256 * 4);

  hipMemsetAsync(p.bar, 0, 256, stream);
  void* args[] = { (void*)&p };
  hipLaunchCooperativeKernel((void*)k_all, dim3(256), dim3(NT), args, 0, stream);
}

// Round 3
// 150.561 us; speedup vs baseline: 4.7826x; 4.7826x over previous
//
#include <hip/hip_runtime.h>
#include <cstdint>

#define B 32
#define D 8732
#define C 21
#define L 32
#define O 8
#define NS 8
#define SLICE 1092     // ceil(D/8)
#define NT 1024

struct Ws {
  const float *loc, *conf, *line, *pose, *dbox, *targets;
  float* out;
  int* cnt;                 // 256 per-(b,slice) positive count (uncapped)
  int* posSlice;            // 256*256 packed (d | cls<<14 | bi<<19)
  float* sce;               // B*D mined-ce
  double *gLossL, *gLossP, *gCeP;                  // 256 partials
  double *gCeNeg;                                  // 32
  double *gDesk, *gNpp, *gNnp, *gTripS, *gTripC;   // 256
};

__device__ inline double waveSumD(double v) {
  #pragma unroll
  for (int s = 32; s > 0; s >>= 1) v += __shfl_down(v, s, 64);
  return v;
}

__device__ inline float iou_one(float tx1, float ty1, float tx2, float ty2, float ta,
                                float px1, float py1, float px2, float py2, float areaB) {
  float lx = fmaxf(tx1, px1), ly = fmaxf(ty1, py1);
  float rx = fminf(tx2, px2), ry = fminf(ty2, py2);
  float iw = fmaxf(rx - lx, 0.f), ih = fmaxf(ry - ly, 0.f);
  float inter = iw * ih;
  return inter / (ta + areaB - inter);
}

// ============ K1: full-D best-prior (redundant per block, kills the k_bp
// dispatch + memset) + per-slice match/CE/losses/compaction. 256 blocks. ============
struct Sh1 {
  float tb[O][4], ta[O], tl[O], tp_[O][3];
  unsigned long long wm[16][O];
  int bpd[O];
  int plist[256];
  int wcnt[16], wbase[16];
  double wred[16][3];
  int run;
};

__global__ __launch_bounds__(NT) void k_match(Ws p) {
  __shared__ Sh1 sh;
  int g = blockIdx.x, tid = threadIdx.x;
  int lane = tid & 63, wav = tid >> 6;
  int b = g >> 3, s = g & 7;
  int dBeg = s * SLICE;
  int dEnd = dBeg + SLICE; if (dEnd > D) dEnd = D;

  if (tid < O) {
    const float* tr = p.targets + ((size_t)b * O + tid) * 9;
    sh.tb[tid][0] = tr[0]; sh.tb[tid][1] = tr[1];
    sh.tb[tid][2] = tr[2]; sh.tb[tid][3] = tr[3];
    sh.ta[tid] = (tr[2] - tr[0]) * (tr[3] - tr[1]);
    sh.tl[tid] = tr[4];
    sh.tp_[tid][0] = tr[5]; sh.tp_[tid][1] = tr[6]; sh.tp_[tid][2] = tr[7];
  }
  if (tid == 0) sh.run = 0;
  __syncthreads();

  // ---- full-D best prior per truth (block-local, no cross-block dep) ----
  {
    unsigned long long key[O];
    #pragma unroll
    for (int t = 0; t < O; t++) key[t] = 0ull;
    for (int d = tid; d < D; d += NT) {
      float4 db = *(const float4*)(p.dbox + (size_t)d * 4);
      float px1 = db.x - 0.5f*db.z, py1 = db.y - 0.5f*db.w;
      float px2 = db.x + 0.5f*db.z, py2 = db.y + 0.5f*db.w;
      float areaB = db.z * db.w;
      #pragma unroll
      for (int t = 0; t < O; t++) {
        float iou = iou_one(sh.tb[t][0], sh.tb[t][1], sh.tb[t][2], sh.tb[t][3],
                            sh.ta[t], px1, py1, px2, py2, areaB);
        unsigned long long kk = ((unsigned long long)__float_as_uint(iou) << 32)
                              | (unsigned long long)(0xFFFFFFFFu - (unsigned)d); // tie -> smaller d
        if (kk > key[t]) key[t] = kk;
      }
    }
    #pragma unroll
    for (int t = 0; t < O; t++) {
      unsigned long long k = key[t];
      #pragma unroll
      for (int sft = 32; sft > 0; sft >>= 1) {
        unsigned long long o = __shfl_down(k, sft, 64);
        if (o > k) k = o;
      }
      if (lane == 0) sh.wm[wav][t] = k;
    }
    __syncthreads();
    if (tid < O) {
      unsigned long long k = sh.wm[0][tid];
      #pragma unroll
      for (int w = 1; w < 16; w++) if (sh.wm[w][tid] > k) k = sh.wm[w][tid];
      sh.bpd[tid] = (int)(0xFFFFFFFFu - (unsigned)(k & 0xFFFFFFFFull));
    }
    __syncthreads();
  }

  // ---- slice loop: match, CE, loc/pose losses, stable compaction ----
  const unsigned long long lt = (lane == 0) ? 0ull : (~0ull >> (64 - lane));
  double ll = 0, lp = 0, cp = 0;
  for (int d0 = dBeg; d0 < dEnd; d0 += NT) {
    int d = d0 + tid;
    bool act = d < dEnd;
    int cls = 0, bi = 0;
    if (act) {
      float4 db = *(const float4*)(p.dbox + (size_t)d * 4);
      float px1 = db.x - 0.5f*db.z, py1 = db.y - 0.5f*db.w;
      float px2 = db.x + 0.5f*db.z, py2 = db.y + 0.5f*db.w;
      float areaB = db.z * db.w;
      float bv = -1.0f;
      #pragma unroll
      for (int t = 0; t < O; t++) {
        float iou = iou_one(sh.tb[t][0], sh.tb[t][1], sh.tb[t][2], sh.tb[t][3],
                            sh.ta[t], px1, py1, px2, py2, areaB);
        if (iou > bv) { bv = iou; bi = t; }     // argmax axis=0: first max wins
      }
      #pragma unroll
      for (int t = O - 1; t >= 0; t--)          // numpy scatter: last truth wins
        if (sh.bpd[t] == d) { bi = t; bv = 2.0f; break; }
      cls = (bv < 0.5f) ? 0 : ((int)sh.tl[bi] + 1);
      const float* cb = p.conf + ((size_t)b * D + d) * C;
      float x[C];
      #pragma unroll
      for (int c = 0; c < C; c++) x[c] = cb[c];
      float m = x[0];
      #pragma unroll
      for (int c = 1; c < C; c++) m = fmaxf(m, x[c]);
      float sm = 0.f;
      #pragma unroll
      for (int c = 0; c < C; c++) sm += __expf(x[c] - m);
      float xc = x[0];
      #pragma unroll
      for (int c = 1; c < C; c++) xc = (cls == c) ? x[c] : xc;
      float ce = m + __logf(sm) - xc;
      size_t bd = (size_t)b * D + d;
      if (cls > 0) {
        cp += ce;
        p.sce[bd] = 0.f;
        float g0 = ((sh.tb[bi][0] + sh.tb[bi][2]) * 0.5f - db.x) / (0.1f * db.z);
        float g1 = ((sh.tb[bi][1] + sh.tb[bi][3]) * 0.5f - db.y) / (0.1f * db.w);
        float g2 = logf((sh.tb[bi][2] - sh.tb[bi][0]) / db.z) / 0.2f;
        float g3 = logf((sh.tb[bi][3] - sh.tb[bi][1]) / db.w) / 0.2f;
        float4 lo = *(const float4*)(p.loc + bd * 4);
        float dv, a;
        dv = lo.x - g0; a = fabsf(dv); ll += (double)((a < 1.f) ? 0.5f*dv*dv : a - 0.5f);
        dv = lo.y - g1; a = fabsf(dv); ll += (double)((a < 1.f) ? 0.5f*dv*dv : a - 0.5f);
        dv = lo.z - g2; a = fabsf(dv); ll += (double)((a < 1.f) ? 0.5f*dv*dv : a - 0.5f);
        dv = lo.w - g3; a = fabsf(dv); ll += (double)((a < 1.f) ? 0.5f*dv*dv : a - 0.5f);
        const float* po = p.pose + bd * 3;
        #pragma unroll
        for (int q = 0; q < 3; q++) {
          float pd = po[q] - sh.tp_[bi][q];
          lp += (double)pd * (double)pd;
        }
      } else {
        p.sce[bd] = fmaxf(ce, 0.f);
      }
    }
    bool pos = act && (cls > 0);
    unsigned long long mm = __ballot(pos);
    if (lane == 0) sh.wcnt[wav] = __popcll(mm);
    __syncthreads();
    if (tid == 0) {
      int r = sh.run;
      #pragma unroll
      for (int w = 0; w < 16; w++) { sh.wbase[w] = r; r += sh.wcnt[w]; }
      sh.run = r;
    }
    __syncthreads();
    if (pos) {
      int rank = sh.wbase[wav] + __popcll(mm & lt);
      if (rank < 256) sh.plist[rank] = d | (cls << 14) | (bi << 19);
    }
    __syncthreads();
  }
  int tot = sh.run;
  if (tid == 0) p.cnt[g] = tot;
  int stored = (tot < 256) ? tot : 256;
  if (tid < stored) p.posSlice[g * 256 + tid] = sh.plist[tid];
  double a0 = waveSumD(ll), a1 = waveSumD(lp), a2 = waveSumD(cp);
  if (lane == 0) { sh.wred[wav][0] = a0; sh.wred[wav][1] = a1; sh.wred[wav][2] = a2; }
  __syncthreads();
  if (tid == 0) {
    double tll = 0, tlp = 0, tcp = 0;
    #pragma unroll
    for (int w = 0; w < 16; w++) { tll += sh.wred[w][0]; tlp += sh.wred[w][1]; tcp += sh.wred[w][2]; }
    p.gLossL[g] = tll; p.gLossP[g] = tlp; p.gCeP[g] = tcp;
  }
}

// ============ K2: blocks 0..31 = per-batch radix top-k; blocks 32..287 =
// pairs row (g-32) with per-block redundant LDS gather. No cross-block dep. ============
struct __align__(16) ShT {
  float sce[D];
  int whist[16][256];
  int hist[256];
  int scb[NS];
  int nposS;
  unsigned prefixSh; int kkSh;
  double wsum[16], wcnt2[16];
};
struct ShP {
  float embT[L][256];     // transposed: column j = row j -> conflict-free
  float nembT[L][256];
  float qp_s[256][3];
  int   lab_s[256];
  float sd[256];
  int   Pi[257];
  int   wscan[4];
  unsigned long long spm[4], snm[4];
  double w1[4];
  int ppc[4], npc[4];
  double wS[16], wC[16];
};
union Sh2 { ShT t; ShP pr; };

__global__ __launch_bounds__(NT) void k_mine(Ws p) {
  __shared__ Sh2 sh;
  int g = blockIdx.x, tid = threadIdx.x;
  int lane = tid & 63, wav = tid >> 6;

  if (g < B) {
    // ---------------- top-k (batch bb) ----------------
    int bb = g;
    if (tid < NS) sh.t.scb[tid] = p.cnt[bb * NS + tid];
    const float* ce = p.sce + (size_t)bb * D;
    for (int i = tid; i < D / 4; i += NT)
      ((float4*)sh.t.sce)[i] = ((const float4*)ce)[i];
    __syncthreads();
    if (tid == 0) {
      int np = 0;
      #pragma unroll
      for (int q = 0; q < NS; q++) np += sh.t.scb[q];
      sh.t.nposS = np;
    }
    __syncthreads();
    int npos = sh.t.nposS;
    int k = npos * 3; if (k > D) k = D;
    unsigned prefix = 0; int kk = k;            // kk >= 1 (npos >= 1 via forced matches)
    for (int pass = 0; pass < 4; pass++) {
      int shift = 24 - 8 * pass;
      for (int i = tid; i < 16 * 256; i += NT) ((int*)sh.t.whist)[i] = 0;
      __syncthreads();
      unsigned himask = (pass == 0) ? 0u : (0xFFFFFFFFu << (shift + 8));
      for (int d = tid; d < D; d += NT) {
        unsigned keyb = __float_as_uint(sh.t.sce[d]);
        if ((keyb & himask) == (prefix & himask))
          atomicAdd(&sh.t.whist[wav][(keyb >> shift) & 255], 1);
      }
      __syncthreads();
      if (tid < 256) {
        int h = 0;
        #pragma unroll
        for (int w = 0; w < 16; w++) h += sh.t.whist[w][tid];
        sh.t.hist[tid] = h;
      }
      __syncthreads();
      if (tid < 64) {
        int l = tid;
        int h0 = sh.t.hist[l*4], h1 = sh.t.hist[l*4+1], h2 = sh.t.hist[l*4+2], h3 = sh.t.hist[l*4+3];
        int loc4 = h0 + h1 + h2 + h3;
        int suf = loc4;
        #pragma unroll
        for (int st = 1; st < 64; st <<= 1) {
          int o = __shfl_down(suf, st, 64);
          if (l + st < 64) suf += o;
        }
        int snext = suf - loc4;
        int s3 = snext + h3, s2 = s3 + h2, s1 = s2 + h1, s0 = s1 + h0;
        if (s3 >= kk && snext < kk) { sh.t.prefixSh = prefix | ((unsigned)(l*4+3) << shift); sh.t.kkSh = kk - snext; }
        if (s2 >= kk && s3 < kk)    { sh.t.prefixSh = prefix | ((unsigned)(l*4+2) << shift); sh.t.kkSh = kk - s3; }
        if (s1 >= kk && s2 < kk)    { sh.t.prefixSh = prefix | ((unsigned)(l*4+1) << shift); sh.t.kkSh = kk - s2; }
        if (s0 >= kk && s1 < kk)    { sh.t.prefixSh = prefix | ((unsigned)(l*4+0) << shift); sh.t.kkSh = kk - s1; }
      }
      __syncthreads();
      prefix = sh.t.prefixSh; kk = sh.t.kkSh;
      __syncthreads();
    }
    float T = __uint_as_float(prefix);
    double sgt = 0.0; int cgt = 0;
    for (int d = tid; d < D; d += NT) {
      float v = sh.t.sce[d];
      if (__float_as_uint(v) > prefix) { sgt += (double)v; cgt++; }
    }
    double wv = waveSumD(sgt);
    double wc = waveSumD((double)cgt);
    if (lane == 0) { sh.t.wsum[wav] = wv; sh.t.wcnt2[wav] = wc; }
    __syncthreads();
    if (tid == 0) {
      double tsg = 0, tcg = 0;
      #pragma unroll
      for (int w = 0; w < 16; w++) { tsg += sh.t.wsum[w]; tcg += sh.t.wcnt2[w]; }
      p.gCeNeg[bb] = tsg + ((double)k - tcg) * (double)T;
    }
  } else {
    // ---------------- pairs row i ----------------
    int i = g - B;
    int qq = tid >> 8, j = tid & 255;

    // parallel inclusive scan of cnt[256] -> Pi[0..256]
    int v = (tid < 256) ? p.cnt[tid] : 0;
    #pragma unroll
    for (int st = 1; st < 64; st <<= 1) {
      int o = __shfl_up(v, st, 64);
      if (lane >= st) v += o;
    }
    if (tid < 256 && lane == 63) sh.pr.wscan[tid >> 6] = v;
    __syncthreads();
    if (tid < 256) {
      int add = 0;
      for (int q = 0; q < (tid >> 6); q++) add += sh.pr.wscan[q];
      sh.pr.Pi[tid + 1] = v + add;
    }
    if (tid == 0) sh.pr.Pi[0] = 0;
    __syncthreads();
    int total = sh.pr.Pi[256];
    int Pc = (total < 256) ? total : 256;

    // redundant gather: slot = tid (0..255) -> (seg, idx) via binary search
    if (tid < 256) {
      int slot = tid;
      bool val = slot < Pc;
      int cls = 0, dpr = 0, seg = 0;
      float q0 = 0.f, q1 = 0.f, q2 = 0.f;
      if (val) {
        int lo = 0;
        #pragma unroll
        for (int st = 128; st > 0; st >>= 1) {
          int m = lo + st;
          if (m <= 255 && sh.pr.Pi[m] <= slot) lo = m;
        }
        seg = lo;
        int idx = slot - sh.pr.Pi[seg];
        if (idx < 256) {
          int packed = p.posSlice[seg * 256 + idx];
          dpr = packed & 0x3FFF;
          cls = (packed >> 14) & 31;
          int bi = (packed >> 19) & 7;
          int bb2 = seg >> 3;
          const float* tr = p.targets + ((size_t)bb2 * O + bi) * 9;
          q0 = tr[5]; q1 = tr[6]; q2 = tr[7];
        } else val = false;
      }
      float nrm2 = 0.f;
      if (val) {
        int bb2 = seg >> 3;
        const float4* e4 = (const float4*)(p.line + ((size_t)bb2 * D + dpr) * L);
        #pragma unroll
        for (int c = 0; c < 8; c++) {
          float4 t4 = e4[c];
          sh.pr.embT[c*4+0][slot] = t4.x; sh.pr.embT[c*4+1][slot] = t4.y;
          sh.pr.embT[c*4+2][slot] = t4.z; sh.pr.embT[c*4+3][slot] = t4.w;
          nrm2 += t4.x*t4.x + t4.y*t4.y + t4.z*t4.z + t4.w*t4.w;
        }
      } else {
        #pragma unroll
        for (int c = 0; c < L; c++) sh.pr.embT[c][slot] = 0.f;
      }
      float inv = 1.f / fmaxf(sqrtf(nrm2), 1e-12f);
      #pragma unroll
      for (int c = 0; c < L; c++) sh.pr.nembT[c][slot] = sh.pr.embT[c][slot] * inv;
      sh.pr.lab_s[slot] = val ? cls : 0;
      sh.pr.qp_s[slot][0] = q0; sh.pr.qp_s[slot][1] = q1; sh.pr.qp_s[slot][2] = q2;
    }
    __syncthreads();

    int li = sh.pr.lab_s[i];
    bool vi = (i < Pc);
    bool pp = false, np = false;
    double dsk = 0.0;
    if (qq == 0) {
      bool vj = (j < Pc);
      float sq = 0.f, esq = 0.f;
      #pragma unroll
      for (int c = 0; c < 8; c++) {
        float d0 = sh.pr.nembT[c*4+0][i] - sh.pr.nembT[c*4+0][j];
        float d1 = sh.pr.nembT[c*4+1][i] - sh.pr.nembT[c*4+1][j];
        float d2 = sh.pr.nembT[c*4+2][i] - sh.pr.nembT[c*4+2][j];
        float d3 = sh.pr.nembT[c*4+3][i] - sh.pr.nembT[c*4+3][j];
        sq += d0*d0 + d1*d1 + d2*d2 + d3*d3;
        float e0 = sh.pr.embT[c*4+0][i] - sh.pr.embT[c*4+0][j];
        float e1 = sh.pr.embT[c*4+1][i] - sh.pr.embT[c*4+1][j];
        float e2 = sh.pr.embT[c*4+2][i] - sh.pr.embT[c*4+2][j];
        float e3 = sh.pr.embT[c*4+3][i] - sh.pr.embT[c*4+3][j];
        esq += e0*e0 + e1*e1 + e2*e2 + e3*e3;
      }
      float dd = sqrtf(fmaxf(sq, 1e-12f));
      sh.pr.sd[j] = dd;
      float qsq = 0.f;
      #pragma unroll
      for (int c = 0; c < 3; c++) {
        float dq = sh.pr.qp_s[i][c] - sh.pr.qp_s[j][c];
        qsq += dq * dq;
      }
      bool vp = vi && vj && (i != j);
      bool same = (li == sh.pr.lab_s[j]);
      pp = vp && same && (dd > 0.2f);
      np = vp && !same && (dd < 0.8f);
      float diff = esq - qsq;
      dsk = pp ? (double)diff * (double)diff : 0.0;
    }
    unsigned long long pb = __ballot(pp), nb = __ballot(np);
    double dw = waveSumD(dsk);
    if (lane == 0 && wav < 4) {
      sh.pr.spm[wav] = pb; sh.pr.snm[wav] = nb; sh.pr.w1[wav] = dw;
      sh.pr.ppc[wav] = (int)__popcll(pb); sh.pr.npc[wav] = (int)__popcll(nb);
    }
    __syncthreads();
    unsigned long long pmw = sh.pr.spm[j >> 6];
    bool pj = (pmw >> (j & 63)) & 1ull;
    float sdj = sh.pr.sd[j];
    double ts = 0.0, tc = 0.0;
    if (pj) {
      for (int it = 0; it < 64; it++) {
        int kx = qq + 4 * it;
        unsigned long long nmw = sh.pr.snm[kx >> 6];
        if ((nmw >> (kx & 63)) & 1ull) {
          float x = sdj - sh.pr.sd[kx] + 0.2f;
          if (x > 0.f) { ts += (double)x; tc += 1.0; }
        }
      }
    }
    ts = waveSumD(ts); tc = waveSumD(tc);
    if (lane == 0) { sh.pr.wS[wav] = ts; sh.pr.wC[wav] = tc; }
    __syncthreads();
    if (tid == 0) {
      double S = 0, Cc = 0;
      #pragma unroll
      for (int w = 0; w < 16; w++) { S += sh.pr.wS[w]; Cc += sh.pr.wC[w]; }
      double dsum = sh.pr.w1[0] + sh.pr.w1[1] + sh.pr.w1[2] + sh.pr.w1[3];
      int pcnt = sh.pr.ppc[0] + sh.pr.ppc[1] + sh.pr.ppc[2] + sh.pr.ppc[3];
      int ncnt = sh.pr.npc[0] + sh.pr.npc[1] + sh.pr.npc[2] + sh.pr.npc[3];
      p.gDesk[i] = dsum; p.gNpp[i] = (double)pcnt; p.gNnp[i] = (double)ncnt;
      p.gTripS[i] = S; p.gTripC[i] = Cc;
    }
  }
}

// ============ K3: final reduce (1 block, 256 thr) ============
__global__ __launch_bounds__(256) void k_fin(Ws p) {
  __shared__ double lbuf[4];
  int tid = threadIdx.x;
  auto sumD = [&](const double* a, int n) -> double {
    double v = 0;
    for (int i = tid; i < n; i += 256) v += a[i];
    v = waveSumD(v);
    __syncthreads();
    if ((tid & 63) == 0) lbuf[tid >> 6] = v;
    __syncthreads();
    double r = lbuf[0] + lbuf[1] + lbuf[2] + lbuf[3];
    __syncthreads();
    return r;
  };
  double lossL = sumD(p.gLossL, 256);
  double lossP = sumD(p.gLossP, 256);
  double ceP   = sumD(p.gCeP,   256);
  double ceN   = sumD(p.gCeNeg,  B);
  double desk  = sumD(p.gDesk,  256);
  double npp   = sumD(p.gNpp,   256);
  double nnp   = sumD(p.gNnp,   256);
  double tripS = sumD(p.gTripS, 256);
  double tripC = sumD(p.gTripC, 256);
  double Ntot;
  {
    double v = 0;
    for (int i = tid; i < 256; i += 256) v += (double)p.cnt[i];
    v = waveSumD(v);
    __syncthreads();
    if ((tid & 63) == 0) lbuf[tid >> 6] = v;
    __syncthreads();
    Ntot = lbuf[0] + lbuf[1] + lbuf[2] + lbuf[3];
  }
  if (tid == 0) {
    double N = (Ntot > 0.0) ? Ntot : 1.0;
    p.out[0] = (float)(lossL / N);
    p.out[1] = (float)((ceP + ceN) / N);
    p.out[2] = (float)(lossP / N);
    double cnt = (tripC > 0.0) ? tripC : 1.0;
    double loss_t = tripS / cnt;
    double nppd = (npp > 0.0) ? npp : 1.0;
    double tot = npp + nnp;
    double denom = (tot > 0.0) ? tot : 1.0;
    double Ldesk = desk / nppd + loss_t / denom;
    Ldesk = Ldesk / nppd / 32.0;
    p.out[3] = (float)Ldesk;
    p.out[4] = (float)loss_t;
  }
}

extern "C" void kernel_launch(void* const* d_in, const int* in_sizes, int n_in,
                              void* d_out, int out_size, void* d_ws, size_t ws_size,
                              hipStream_t stream) {
  char* ws = (char*)d_ws;
  size_t off = 0;
  auto alloc = [&](size_t bytes) -> char* {
    char* q = ws + off;
    off += (bytes + 255) & ~(size_t)255;
    return q;
  };
  Ws p;
  p.loc     = (const float*)d_in[0];
  p.conf    = (const float*)d_in[1];
  p.line    = (const float*)d_in[2];
  p.pose    = (const float*)d_in[3];
  p.dbox    = (const float*)d_in[4];
  p.targets = (const float*)d_in[5];
  p.out     = (float*)d_out;
  p.cnt      = (int*)alloc(256 * 4);
  p.posSlice = (int*)alloc(256 * 256 * 4);
  p.sce      = (float*)alloc((size_t)B * D * 4);
  p.gLossL   = (double*)alloc(256 * 8);
  p.gLossP   = (double*)alloc(256 * 8);
  p.gCeP     = (double*)alloc(256 * 8);
  p.gCeNeg   = (double*)alloc(B * 8);
  p.gDesk    = (double*)alloc(256 * 8);
  p.gNpp     = (double*)alloc(256 * 8);
  p.gNnp     = (double*)alloc(256 * 8);
  p.gTripS   = (double*)alloc(256 * 8);
  p.gTripC   = (double*)alloc(256 * 8);

  k_match<<<256,     NT, 0, stream>>>(p);
  k_mine <<<256 + B, NT, 0, stream>>>(p);
  k_fin  <<<1,      256, 0, stream>>>(p);
}